// Round 4
// baseline (519.272 us; speedup 1.0000x reference)
//
#include <hip/hip_runtime.h>

// MultiHeadEncoderDecoderAttention: N=2, H=16, T1=T2=2048, HIDDEN=1024, d=64
// out = relu( softmax(Q K^T + mask) V @ W^T + b ), no 1/sqrt(d) scaling.
//
// Round 4: attn and proj have ZERO LDS and ZERO barriers — all fragments come
// straight from global (L1/L2-resident). prep produces head-major K [b,h,key,64]
// and transposed V [b,h,dim,T2] so the fragment loads are dense. Grid raised to
// 1024 blocks (4/CU, 16 waves/CU) for both attn and proj; launch_bounds(256,4)
// pins VGPR <= 128. r3 lesson: both pipes were ~21% at Occ 20% -> latency-bound,
// barriers + grid limit were the stall, not VALU/MFMA/BW.

typedef short short8 __attribute__((ext_vector_type(8)));
typedef short short4v __attribute__((ext_vector_type(4)));
typedef float floatx4 __attribute__((ext_vector_type(4)));

#define HIDDEN 1024
#define HEADS 16
#define NB 2
#define T1 2048
#define T2 2048

#define LOG2E 1.44269504f
#define SHIFT 28.8539004f  // 20*log2e; exp(s-20) == exp2(s*log2e - SHIFT)

__device__ __forceinline__ float fexp2(float x) {
#if __has_builtin(__builtin_amdgcn_exp2f)
    return __builtin_amdgcn_exp2f(x);   // v_exp_f32
#else
    return __expf(x * 0.69314718056f);
#endif
}

__device__ __forceinline__ unsigned short f2bf(float f) {  // RNE
    unsigned u = __float_as_uint(f);
    return (unsigned short)((u + 0x7fffu + ((u >> 16) & 1u)) >> 16);
}

// pack bf16-trunc(a) low16 | bf16-trunc(b) high16 in ONE v_perm_b32
__device__ __forceinline__ int pk_hi16(float a, float b) {
    return (int)__builtin_amdgcn_perm(__float_as_uint(b), __float_as_uint(a), 0x07060302u);
}

union S4 { int2 i2; short4v s; };

__global__ void zero_kernel(unsigned* f) {
    if (threadIdx.x == 0) *f = 0u;
}

// y==0: cvt K (head-major) + W. y==1: mask absmax -> flag. y==2: V cvt+transpose.
__global__ __launch_bounds__(256) void prep_kernel(
        const float4* __restrict__ ek, const float4* __restrict__ ev,
        const float4* __restrict__ ww, const float4* __restrict__ mask,
        ushort4* __restrict__ Khm,   // [NB,H,T2,64] bf16 head-major (ushort4 units)
        ushort4* __restrict__ Wb,    // [1024,1024] bf16
        short*   __restrict__ Vt,    // [NB,H,64,T2] bf16 transposed
        unsigned* __restrict__ flag)
{
    __shared__ short lds[64 * 68];
    const int t = threadIdx.x;
    if (blockIdx.y == 0) {
        const int NKf4 = NB * T2 * HIDDEN / 4;          // 1048576
        const int n = NKf4 + HIDDEN * HIDDEN / 4;       // +262144
        int i = blockIdx.x * 256 + t;
        const int stride = gridDim.x * 256;
        for (; i < n; i += stride) {
            if (i < NKf4) {
                float4 v = ek[i];
                ushort4 o;
                o.x = f2bf(v.x); o.y = f2bf(v.y); o.z = f2bf(v.z); o.w = f2bf(v.w);
                int b = i >> 19, r = i & 524287;        // T2*256 = 2^19
                int key = r >> 8, c4 = r & 255;
                int h = c4 >> 4, d4 = c4 & 15;
                Khm[(((b * 16 + h) * 2048 + key) << 4) + d4] = o;
            } else {
                float4 v = ww[i - NKf4];
                ushort4 o;
                o.x = f2bf(v.x); o.y = f2bf(v.y); o.z = f2bf(v.z); o.w = f2bf(v.w);
                Wb[i - NKf4] = o;
            }
        }
    } else if (blockIdx.y == 1) {
        const int NM = NB * T2 * T2 / 4;
        int i = blockIdx.x * 256 + t;
        const int stride = gridDim.x * 256;
        float mx = 0.f;
        for (; i < NM; i += stride) {
            float4 v = mask[i];
            mx = fmaxf(mx, fmaxf(fmaxf(fabsf(v.x), fabsf(v.y)), fmaxf(fabsf(v.z), fabsf(v.w))));
        }
        for (int d = 32; d; d >>= 1) mx = fmaxf(mx, __shfl_xor(mx, d));
        if ((t & 63) == 0 && mx > 0.f) atomicMax(flag, __float_as_uint(mx));
    } else {
        // V transpose: 64 keys x 64 dims tile per block; 1024 blocks exactly.
        const int x = blockIdx.x;
        const int kt = x & 31, h = (x >> 5) & 15, b = x >> 9;
        const int key0 = kt * 64;
#pragma unroll
        for (int it = 0; it < 4; ++it) {
            int idx = t + it * 256;
            int key = idx >> 4, f4 = idx & 15;
            float4 v = ev[(b * T2 + key0 + key) * 256 + h * 16 + f4];
            short4v o;
            o[0] = (short)f2bf(v.x); o[1] = (short)f2bf(v.y);
            o[2] = (short)f2bf(v.z); o[3] = (short)f2bf(v.w);
            *(short4v*)&lds[key * 68 + f4 * 4] = o;    // [key][dim], stride 68 (8B-aligned)
        }
        __syncthreads();
        const int dim = t >> 2, kq = t & 3;
        short8 s0, s1;
#pragma unroll
        for (int kk = 0; kk < 8; ++kk) s0[kk] = lds[(kq * 16 + kk) * 68 + dim];
#pragma unroll
        for (int kk = 0; kk < 8; ++kk) s1[kk] = lds[(kq * 16 + 8 + kk) * 68 + dim];
        short* Vr = Vt + ((b * 16 + h) * 64 + dim) * T2 + key0 + kq * 16;
        *(short8*)&Vr[0] = s0;
        *(short8*)&Vr[8] = s1;
    }
}

// Flash attention, no LDS, no barriers. Grid (T1/64, HEADS, NB) = 1024 blocks.
// Each wave owns 16 q rows; lane l16 = q row, quad*4+r = key (S^T C-layout).
__global__ __launch_bounds__(256, 4) void attn_kernel(
        const float* __restrict__ q,       // [NB,T1,HIDDEN] fp32
        const short* __restrict__ Khm,     // [NB,H,T2,64] bf16
        const short* __restrict__ Vt,      // [NB,H,64,T2] bf16
        const float* __restrict__ mask,    // [NB,1,T2,T2] fp32
        const unsigned* __restrict__ flagp,
        short* __restrict__ ctx)           // [NB,T1,HIDDEN] bf16
{
    const int tid = threadIdx.x;
    const int wave = tid >> 6;
    const int lane = tid & 63;
    const int quad = lane >> 4;
    const int l16 = lane & 15;

    const int b = blockIdx.z;
    const int h = blockIdx.y;
    const int qrow = blockIdx.x * 64 + wave * 16 + l16;

    const bool use_mask = (*flagp != 0u);

    // Q frag (B-operand of QK: B[k=dim=quad*8+j][n=qrow=l16]), pre-scaled by log2e
    short8 qf[2];
#pragma unroll
    for (int ks = 0; ks < 2; ++ks) {
        const float* qp = q + (((b * T1) + qrow) << 10) + (h << 6) + ks * 32 + quad * 8;
        float4 v0 = *(const float4*)qp;
        float4 v1 = *(const float4*)(qp + 4);
        short8 s;
        s[0] = (short)f2bf(v0.x * LOG2E); s[1] = (short)f2bf(v0.y * LOG2E);
        s[2] = (short)f2bf(v0.z * LOG2E); s[3] = (short)f2bf(v0.w * LOG2E);
        s[4] = (short)f2bf(v1.x * LOG2E); s[5] = (short)f2bf(v1.y * LOG2E);
        s[6] = (short)f2bf(v1.z * LOG2E); s[7] = (short)f2bf(v1.w * LOG2E);
        qf[ks] = s;
    }

    floatx4 o_acc[4], o_l;
#pragma unroll
    for (int cb = 0; cb < 4; ++cb) o_acc[cb] = (floatx4){0.f, 0.f, 0.f, 0.f};
    o_l = (floatx4){0.f, 0.f, 0.f, 0.f};
    short4v ones;
#pragma unroll
    for (int j = 0; j < 4; ++j) ones[j] = (short)0x3F80;

    const short* Kp = Khm + ((b * 16 + h) * 2048) * 64;
    const short* Vp = Vt + ((b * 16 + h) * 64) * 2048;
    const float* mrow = mask + ((long)(b * T2) + qrow) * T2;

    for (int kc = 0; kc < T2; kc += 64) {
        // K frags (A-operand of QK: A[m=key=l16][k=dim=quad*8+j]) — b128, dense rows
        short8 kf[4][2];
#pragma unroll
        for (int kb = 0; kb < 4; ++kb)
#pragma unroll
            for (int ks = 0; ks < 2; ++ks)
                kf[kb][ks] = *(const short8*)&Kp[(kc + kb * 16 + l16) * 64 + ks * 32 + quad * 8];

        // V^T frags (A-operand of PV: A[m=dim=l16][k=key=quad*4+j]) — b64 from Vt
        short4v vf[4][4];
#pragma unroll
        for (int kb = 0; kb < 4; ++kb)
#pragma unroll
            for (int cb = 0; cb < 4; ++cb)
                vf[kb][cb] = *(const short4v*)&Vp[(cb * 16 + l16) * 2048 + kc + kb * 16 + quad * 4];

        // S^T - SHIFT
        floatx4 st[4];
#pragma unroll
        for (int kb = 0; kb < 4; ++kb) {
            floatx4 a = (floatx4){-SHIFT, -SHIFT, -SHIFT, -SHIFT};
            a = __builtin_amdgcn_mfma_f32_16x16x32_bf16(kf[kb][0], qf[0], a, 0, 0, 0);
            a = __builtin_amdgcn_mfma_f32_16x16x32_bf16(kf[kb][1], qf[1], a, 0, 0, 0);
            st[kb] = a;
        }
        if (use_mask) {
#pragma unroll
            for (int kb = 0; kb < 4; ++kb)
#pragma unroll
                for (int r = 0; r < 4; ++r)
                    st[kb][r] += mrow[kc + kb * 16 + quad * 4 + r] * LOG2E;
        }
        // p = exp2(st), pack to bf16 (trunc, bias cancels vs ones-MFMA l)
        short4v pf[4];
#pragma unroll
        for (int kb = 0; kb < 4; ++kb) {
            float p0 = fexp2(st[kb][0]);
            float p1 = fexp2(st[kb][1]);
            float p2 = fexp2(st[kb][2]);
            float p3 = fexp2(st[kb][3]);
            S4 u; u.i2 = make_int2(pk_hi16(p0, p1), pk_hi16(p2, p3));
            pf[kb] = u.s;
        }
        // PV: O^T[dim][q] += V^T x P; l via ones-row MFMA on same truncated P
#pragma unroll
        for (int kb = 0; kb < 4; ++kb) {
            o_l = __builtin_amdgcn_mfma_f32_16x16x16bf16_1k(ones, pf[kb], o_l, 0, 0, 0);
#pragma unroll
            for (int cb = 0; cb < 4; ++cb)
                o_acc[cb] = __builtin_amdgcn_mfma_f32_16x16x16bf16_1k(
                    vf[kb][cb], pf[kb], o_acc[cb], 0, 0, 0);
        }
    }

    // epilogue: lane holds O^T[dim=cb*16+quad*4+r][q=l16]; l same across quads/r
    const float rinv = 1.0f / o_l[0];
#pragma unroll
    for (int cb = 0; cb < 4; ++cb) {
        short4v o;
#pragma unroll
        for (int r = 0; r < 4; ++r) o[r] = (short)f2bf(o_acc[cb][r] * rinv);
        *(short4v*)&ctx[((b * T1 + qrow) << 10) + (h << 6) + cb * 16 + quad * 4] = o;
    }
}

// Projection: out[m][n] = relu( sum_k ctx[m][k]*W[n][k] + bias[n] ).
// No LDS, no barriers: A/B frags direct from global (W 2MB L2-resident).
// Grid (64,16) = 1024 blocks; block 64x64 tile; wave 32x32 (2x2 waves).
__global__ __launch_bounds__(256, 4) void proj_kernel(
        const short* __restrict__ Cb,   // [4096,1024] bf16
        const short* __restrict__ Wb,   // [1024,1024] bf16
        const float* __restrict__ bias, // [1024]
        float* __restrict__ out)        // [4096,1024] fp32
{
    const int tid = threadIdx.x;
    const int wave = tid >> 6;
    const int lane = tid & 63;
    const int quad = lane >> 4;
    const int l16 = lane & 15;
    const int wm = wave >> 1, wn = wave & 1;
    const int m0 = blockIdx.x * 64 + wm * 32;
    const int n0 = blockIdx.y * 64 + wn * 32;

    const short* Arow = Cb + (m0 + l16) * 1024 + quad * 8;
    const short* Brow = Wb + (n0 + l16) * 1024 + quad * 8;

    floatx4 acc[2][2];
#pragma unroll
    for (int i = 0; i < 2; ++i)
#pragma unroll
        for (int j = 0; j < 2; ++j) acc[i][j] = (floatx4){0.f, 0.f, 0.f, 0.f};

    for (int kt = 0; kt < 1024; kt += 32) {
        short8 af[2], bf[2];
#pragma unroll
        for (int i = 0; i < 2; ++i) af[i] = *(const short8*)&Arow[i * 16 * 1024 + kt];
#pragma unroll
        for (int j = 0; j < 2; ++j) bf[j] = *(const short8*)&Brow[j * 16 * 1024 + kt];
#pragma unroll
        for (int i = 0; i < 2; ++i)
#pragma unroll
            for (int j = 0; j < 2; ++j)
                acc[i][j] = __builtin_amdgcn_mfma_f32_16x16x32_bf16(af[i], bf[j], acc[i][j], 0, 0, 0);
    }

    float bv[2];
#pragma unroll
    for (int j = 0; j < 2; ++j) bv[j] = bias[n0 + j * 16 + l16];

#pragma unroll
    for (int i = 0; i < 2; ++i)
#pragma unroll
        for (int j = 0; j < 2; ++j)
#pragma unroll
            for (int r = 0; r < 4; ++r) {
                int row = m0 + i * 16 + quad * 4 + r;
                int col = n0 + j * 16 + l16;
                out[(row << 10) + col] = fmaxf(acc[i][j][r] + bv[j], 0.f);
            }
}

extern "C" void kernel_launch(void* const* d_in, const int* in_sizes, int n_in,
                              void* d_out, int out_size, void* d_ws, size_t ws_size,
                              hipStream_t stream) {
    const float* q    = (const float*)d_in[0];
    const float* ek   = (const float*)d_in[1];
    const float* ev   = (const float*)d_in[2];
    const float* mask = (const float*)d_in[3];
    const float* wo_w = (const float*)d_in[4];
    const float* wo_b = (const float*)d_in[5];
    float* out = (float*)d_out;

    char* ws = (char*)d_ws;
    unsigned* flag = (unsigned*)ws;
    short* Khm = (short*)(ws + 4096);
    short* Wb  = Khm + (NB * T2 * HIDDEN);   // 8.4 MB
    short* Vt  = Wb + (HIDDEN * HIDDEN);     // +2 MB
    short* Cb  = Vt + (NB * T2 * HIDDEN);    // +8.4 MB
    // total ws use: 4096 + 8388608 + 2097152 + 8388608 + 8388608 = 27,267,072 B

    zero_kernel<<<1, 64, 0, stream>>>(flag);
    prep_kernel<<<dim3(1024, 3), 256, 0, stream>>>(
        (const float4*)ek, (const float4*)ev, (const float4*)wo_w, (const float4*)mask,
        (ushort4*)Khm, (ushort4*)Wb, Vt, flag);
    attn_kernel<<<dim3(T1 / 64, HEADS, NB), 256, 0, stream>>>(q, Khm, Vt, mask, flag, Cb);
    proj_kernel<<<dim3(64, 16), 256, 0, stream>>>(Cb, Wb, wo_b, out);
}

// Round 5
// 272.130 us; speedup vs baseline: 1.9082x; 1.9082x over previous
//
#include <hip/hip_runtime.h>

// MultiHeadEncoderDecoderAttention: N=2, H=16, T1=T2=2048, HIDDEN=1024, d=64
// out = relu( softmax(Q K^T + mask) V @ W^T + b ), no 1/sqrt(d) scaling.
//
// Round 5: r3 LDS structure (known-good codegen) + r4's data layouts.
// attn: q-tile 64 (4 waves x 16 rows) -> 1024 blocks (4/CU, 16 waves/CU);
// V staged into LDS from pre-transposed Vt via b128 load + b128 LDS write
// (stride 72 shorts = 144B, 16B-aligned); K frags from head-major Khm (dense
// 128B rows, L1-shared by the block's 4 waves). One barrier per chunk.
// r4 lesson: NO min-waves launch bound, no per-wave global fragment gather.
// proj: r2's 128x128 LDS version (r3's 64x128 split regressed).

typedef short short8 __attribute__((ext_vector_type(8)));
typedef short short4v __attribute__((ext_vector_type(4)));
typedef float floatx4 __attribute__((ext_vector_type(4)));

#define HIDDEN 1024
#define HEADS 16
#define NB 2
#define T1 2048
#define T2 2048

#define LOG2E 1.44269504f
#define SHIFT 28.8539004f  // 20*log2e; exp(s-20) == exp2(s*log2e - SHIFT)
#define VS 72              // lV row stride in shorts (144 B, 16B-aligned)

__device__ __forceinline__ float fexp2(float x) {
#if __has_builtin(__builtin_amdgcn_exp2f)
    return __builtin_amdgcn_exp2f(x);   // v_exp_f32
#else
    return __expf(x * 0.69314718056f);
#endif
}

__device__ __forceinline__ unsigned short f2bf(float f) {  // RNE
    unsigned u = __float_as_uint(f);
    return (unsigned short)((u + 0x7fffu + ((u >> 16) & 1u)) >> 16);
}

// pack bf16-trunc(a) low16 | bf16-trunc(b) high16 in ONE v_perm_b32
__device__ __forceinline__ int pk_hi16(float a, float b) {
    return (int)__builtin_amdgcn_perm(__float_as_uint(b), __float_as_uint(a), 0x07060302u);
}

union S4 { int2 i2; short4v s; };

__global__ void zero_kernel(unsigned* f) {
    if (threadIdx.x == 0) *f = 0u;
}

// y==0: cvt K (head-major) + W. y==1: mask absmax -> flag. y==2: V cvt+transpose.
__global__ __launch_bounds__(256) void prep_kernel(
        const float4* __restrict__ ek, const float4* __restrict__ ev,
        const float4* __restrict__ ww, const float4* __restrict__ mask,
        ushort4* __restrict__ Khm,   // [NB,H,T2,64] bf16 head-major (ushort4 units)
        ushort4* __restrict__ Wb,    // [1024,1024] bf16
        short*   __restrict__ Vt,    // [NB,H,64,T2] bf16 transposed
        unsigned* __restrict__ flag)
{
    __shared__ short lds[64 * 68];
    const int t = threadIdx.x;
    if (blockIdx.y == 0) {
        const int NKf4 = NB * T2 * HIDDEN / 4;          // 1048576
        const int n = NKf4 + HIDDEN * HIDDEN / 4;       // +262144
        int i = blockIdx.x * 256 + t;
        const int stride = gridDim.x * 256;
        for (; i < n; i += stride) {
            if (i < NKf4) {
                float4 v = ek[i];
                ushort4 o;
                o.x = f2bf(v.x); o.y = f2bf(v.y); o.z = f2bf(v.z); o.w = f2bf(v.w);
                int b = i >> 19, r = i & 524287;        // T2*256 = 2^19
                int key = r >> 8, c4 = r & 255;
                int h = c4 >> 4, d4 = c4 & 15;
                Khm[(((b * 16 + h) * 2048 + key) << 4) + d4] = o;
            } else {
                float4 v = ww[i - NKf4];
                ushort4 o;
                o.x = f2bf(v.x); o.y = f2bf(v.y); o.z = f2bf(v.z); o.w = f2bf(v.w);
                Wb[i - NKf4] = o;
            }
        }
    } else if (blockIdx.y == 1) {
        const int NM = NB * T2 * T2 / 4;
        int i = blockIdx.x * 256 + t;
        const int stride = gridDim.x * 256;
        float mx = 0.f;
        for (; i < NM; i += stride) {
            float4 v = mask[i];
            mx = fmaxf(mx, fmaxf(fmaxf(fabsf(v.x), fabsf(v.y)), fmaxf(fabsf(v.z), fabsf(v.w))));
        }
        for (int d = 32; d; d >>= 1) mx = fmaxf(mx, __shfl_xor(mx, d));
        if ((t & 63) == 0 && mx > 0.f) atomicMax(flag, __float_as_uint(mx));
    } else {
        // V transpose: 64 keys x 64 dims tile per block; 1024 blocks exactly.
        const int x = blockIdx.x;
        const int kt = x & 31, h = (x >> 5) & 15, b = x >> 9;
        const int key0 = kt * 64;
#pragma unroll
        for (int it = 0; it < 4; ++it) {
            int idx = t + it * 256;
            int key = idx >> 4, f4 = idx & 15;
            float4 v = ev[(b * T2 + key0 + key) * 256 + h * 16 + f4];
            short4v o;
            o[0] = (short)f2bf(v.x); o[1] = (short)f2bf(v.y);
            o[2] = (short)f2bf(v.z); o[3] = (short)f2bf(v.w);
            *(short4v*)&lds[key * 68 + f4 * 4] = o;    // [key][dim], stride 68 (8B-aligned)
        }
        __syncthreads();
        const int dim = t >> 2, kq = t & 3;
        short8 s0, s1;
#pragma unroll
        for (int kk = 0; kk < 8; ++kk) s0[kk] = lds[(kq * 16 + kk) * 68 + dim];
#pragma unroll
        for (int kk = 0; kk < 8; ++kk) s1[kk] = lds[(kq * 16 + 8 + kk) * 68 + dim];
        short* Vr = Vt + ((b * 16 + h) * 64 + dim) * T2 + key0 + kq * 16;
        *(short8*)&Vr[0] = s0;
        *(short8*)&Vr[8] = s1;
    }
}

// Flash attention. Grid (T1/64, HEADS, NB) = 1024 blocks, 4 waves x 16 q-rows.
__global__ __launch_bounds__(256) void attn_kernel(
        const float* __restrict__ q,       // [NB,T1,HIDDEN] fp32
        const short* __restrict__ Khm,     // [NB,H,T2,64] bf16 head-major
        const short* __restrict__ Vt,      // [NB,H,64,T2] bf16 transposed
        const float* __restrict__ mask,    // [NB,1,T2,T2] fp32
        const unsigned* __restrict__ flagp,
        short* __restrict__ ctx)           // [NB,T1,HIDDEN] bf16
{
    __shared__ short lV[2][64 * VS];       // [dim][key], double-buffered

    const int tid = threadIdx.x;
    const int wave = tid >> 6;
    const int lane = tid & 63;
    const int quad = lane >> 4;
    const int l16 = lane & 15;

    const int b = blockIdx.z;
    const int h = blockIdx.y;
    const int qrow = blockIdx.x * 64 + wave * 16 + l16;

    const bool use_mask = (*flagp != 0u);

    const short* Kp = Khm + ((b * 16 + h) * 2048) * 64;
    const short* Vp = Vt + ((b * 16 + h) * 64) * 2048;
    const float* mrow = mask + ((long)(b * T2) + qrow) * T2;

    // Q frag (B-operand of QK: B[k=dim=quad*8+j][n=qrow=l16]), pre-scaled by log2e
    short8 qf[2];
#pragma unroll
    for (int ks = 0; ks < 2; ++ks) {
        const float* qp = q + (((b * T1) + qrow) << 10) + (h << 6) + ks * 32 + quad * 8;
        float4 v0 = *(const float4*)qp;
        float4 v1 = *(const float4*)(qp + 4);
        short8 s;
        s[0] = (short)f2bf(v0.x * LOG2E); s[1] = (short)f2bf(v0.y * LOG2E);
        s[2] = (short)f2bf(v0.z * LOG2E); s[3] = (short)f2bf(v0.w * LOG2E);
        s[4] = (short)f2bf(v1.x * LOG2E); s[5] = (short)f2bf(v1.y * LOG2E);
        s[6] = (short)f2bf(v1.z * LOG2E); s[7] = (short)f2bf(v1.w * LOG2E);
        qf[ks] = s;
    }

    floatx4 o_acc[4], o_l;
#pragma unroll
    for (int cb = 0; cb < 4; ++cb) o_acc[cb] = (floatx4){0.f, 0.f, 0.f, 0.f};
    o_l = (floatx4){0.f, 0.f, 0.f, 0.f};
    short4v ones;
#pragma unroll
    for (int j = 0; j < 4; ++j) ones[j] = (short)0x3F80;

    // stage chunk 0: lV[dim][key] direct b128 copies from Vt (dense rows)
#pragma unroll
    for (int it = 0; it < 2; ++it) {
        int c = tid + it * 256;
        int dim = c >> 3, kb8 = c & 7;
        *(short8*)&lV[0][dim * VS + kb8 * 8] = *(const short8*)&Vp[dim * 2048 + kb8 * 8];
    }
    __syncthreads();

    for (int ic = 0; ic < T2 / 64; ++ic) {
        const int kc = ic << 6;
        const short* cur = lV[ic & 1];
        if (ic + 1 < T2 / 64) {
            short* nxt = lV[(ic + 1) & 1];
#pragma unroll
            for (int it = 0; it < 2; ++it) {
                int c = tid + it * 256;
                int dim = c >> 3, kb8 = c & 7;
                *(short8*)&nxt[dim * VS + kb8 * 8] =
                    *(const short8*)&Vp[dim * 2048 + kc + 64 + kb8 * 8];
            }
        }

        // K frags (A-operand of QK: A[m=key=l16][k=dim=quad*8+j]) — dense 128B rows
        short8 kf[4][2];
#pragma unroll
        for (int kb = 0; kb < 4; ++kb)
#pragma unroll
            for (int ks = 0; ks < 2; ++ks)
                kf[kb][ks] = *(const short8*)&Kp[(kc + kb * 16 + l16) * 64 + ks * 32 + quad * 8];

        // V^T frags (A-operand of PV: A[m=dim=l16][k=key=quad*4+j]) — b64, ~2-way banks
        short4v vf[4][4];
#pragma unroll
        for (int kb = 0; kb < 4; ++kb)
#pragma unroll
            for (int cb = 0; cb < 4; ++cb)
                vf[kb][cb] = *(const short4v*)&cur[(cb * 16 + l16) * VS + kb * 16 + quad * 4];

        // S^T - SHIFT via accumulator init
        floatx4 st[4];
#pragma unroll
        for (int kb = 0; kb < 4; ++kb) {
            floatx4 a = (floatx4){-SHIFT, -SHIFT, -SHIFT, -SHIFT};
            a = __builtin_amdgcn_mfma_f32_16x16x32_bf16(kf[kb][0], qf[0], a, 0, 0, 0);
            a = __builtin_amdgcn_mfma_f32_16x16x32_bf16(kf[kb][1], qf[1], a, 0, 0, 0);
            st[kb] = a;
        }
        if (use_mask) {
#pragma unroll
            for (int kb = 0; kb < 4; ++kb)
#pragma unroll
                for (int r = 0; r < 4; ++r)
                    st[kb][r] += mrow[kc + kb * 16 + quad * 4 + r] * LOG2E;
        }
        // p = exp2(st), pack to bf16 (trunc; bias cancels vs ones-MFMA l)
        short4v pf[4];
#pragma unroll
        for (int kb = 0; kb < 4; ++kb) {
            float p0 = fexp2(st[kb][0]);
            float p1 = fexp2(st[kb][1]);
            float p2 = fexp2(st[kb][2]);
            float p3 = fexp2(st[kb][3]);
            S4 u; u.i2 = make_int2(pk_hi16(p0, p1), pk_hi16(p2, p3));
            pf[kb] = u.s;
        }
        // PV: O^T[dim][q] += V^T x P; l via ones-row MFMA on same truncated P
#pragma unroll
        for (int kb = 0; kb < 4; ++kb) {
            o_l = __builtin_amdgcn_mfma_f32_16x16x16bf16_1k(ones, pf[kb], o_l, 0, 0, 0);
#pragma unroll
            for (int cb = 0; cb < 4; ++cb)
                o_acc[cb] = __builtin_amdgcn_mfma_f32_16x16x16bf16_1k(
                    vf[kb][cb], pf[kb], o_acc[cb], 0, 0, 0);
        }
        __syncthreads();
    }

    // epilogue: lane holds O^T[dim=cb*16+quad*4+r][q=l16]; l same across quads/r
    const float rinv = 1.0f / o_l[0];
#pragma unroll
    for (int cb = 0; cb < 4; ++cb) {
        short4v o;
#pragma unroll
        for (int r = 0; r < 4; ++r) o[r] = (short)f2bf(o_acc[cb][r] * rinv);
        *(short4v*)&ctx[((b * T1 + qrow) << 10) + (h << 6) + cb * 16 + quad * 4] = o;
    }
}

// Projection: out[m][n] = relu( sum_k ctx[m][k] * W[n][k] + bias[n] )
// r2 config: tile 128x128, grid (32,8), 4 waves 2x2, BK=64.
__global__ __launch_bounds__(256) void proj_kernel(
        const short* __restrict__ Cb,   // [4096, 1024] bf16
        const short* __restrict__ Wb,   // [1024, 1024] bf16
        const float* __restrict__ bias, // [1024]
        float* __restrict__ out)        // [4096, 1024] fp32
{
    __shared__ short lA[128 * 72];
    __shared__ short lB[128 * 72];

    const int tid = threadIdx.x;
    const int wave = tid >> 6;
    const int lane = tid & 63;
    const int quad = lane >> 4;
    const int l16 = lane & 15;
    const int wm = wave >> 1, wn = wave & 1;
    const int bm = blockIdx.x, bn = blockIdx.y;

    floatx4 acc[4][4];
#pragma unroll
    for (int i = 0; i < 4; ++i)
#pragma unroll
        for (int j = 0; j < 4; ++j) acc[i][j] = (floatx4){0.f, 0.f, 0.f, 0.f};

    for (int kt = 0; kt < 1024; kt += 64) {
#pragma unroll
        for (int it = 0; it < 4; ++it) {
            int i = tid + it * 256;
            int row = i >> 3, c = i & 7;
            *(short8*)&lA[row * 72 + c * 8] =
                *(const short8*)&Cb[((bm * 128 + row) << 10) + kt + c * 8];
            *(short8*)&lB[row * 72 + c * 8] =
                *(const short8*)&Wb[((bn * 128 + row) << 10) + kt + c * 8];
        }
        __syncthreads();
#pragma unroll
        for (int ks = 0; ks < 2; ++ks) {
            short8 af[4], bf[4];
#pragma unroll
            for (int i = 0; i < 4; ++i) {
                af[i] = *(const short8*)&lA[(wm * 64 + i * 16 + l16) * 72 + ks * 32 + quad * 8];
                bf[i] = *(const short8*)&lB[(wn * 64 + i * 16 + l16) * 72 + ks * 32 + quad * 8];
            }
#pragma unroll
            for (int i = 0; i < 4; ++i)
#pragma unroll
                for (int j = 0; j < 4; ++j)
                    acc[i][j] = __builtin_amdgcn_mfma_f32_16x16x32_bf16(af[i], bf[j], acc[i][j], 0, 0, 0);
        }
        __syncthreads();
    }

    float bv[4];
#pragma unroll
    for (int j = 0; j < 4; ++j) bv[j] = bias[bn * 128 + wn * 64 + j * 16 + l16];

#pragma unroll
    for (int i = 0; i < 4; ++i)
#pragma unroll
        for (int j = 0; j < 4; ++j)
#pragma unroll
            for (int r = 0; r < 4; ++r) {
                int row = bm * 128 + wm * 64 + i * 16 + quad * 4 + r;
                int col = bn * 128 + wn * 64 + j * 16 + l16;
                float v = acc[i][j][r] + bv[j];
                out[(row << 10) + col] = fmaxf(v, 0.f);
            }
}

extern "C" void kernel_launch(void* const* d_in, const int* in_sizes, int n_in,
                              void* d_out, int out_size, void* d_ws, size_t ws_size,
                              hipStream_t stream) {
    const float* q    = (const float*)d_in[0];
    const float* ek   = (const float*)d_in[1];
    const float* ev   = (const float*)d_in[2];
    const float* mask = (const float*)d_in[3];
    const float* wo_w = (const float*)d_in[4];
    const float* wo_b = (const float*)d_in[5];
    float* out = (float*)d_out;

    char* ws = (char*)d_ws;
    unsigned* flag = (unsigned*)ws;
    short* Khm = (short*)(ws + 4096);
    short* Wb  = Khm + (NB * T2 * HIDDEN);   // 8.4 MB
    short* Vt  = Wb + (HIDDEN * HIDDEN);     // +2 MB
    short* Cb  = Vt + (NB * T2 * HIDDEN);    // +8.4 MB
    // total ws use: 4096 + 8388608 + 2097152 + 8388608 + 8388608 = 27,267,072 B

    zero_kernel<<<1, 64, 0, stream>>>(flag);
    prep_kernel<<<dim3(1024, 3), 256, 0, stream>>>(
        (const float4*)ek, (const float4*)ev, (const float4*)wo_w, (const float4*)mask,
        (ushort4*)Khm, (ushort4*)Wb, Vt, flag);
    attn_kernel<<<dim3(T1 / 64, HEADS, NB), 256, 0, stream>>>(q, Khm, Vt, mask, flag, Cb);
    proj_kernel<<<dim3(32, 8), 256, 0, stream>>>(Cb, Wb, wo_b, out);
}